// Round 10
// baseline (93.301 us; speedup 1.0000x reference)
//
#include <hip/hip_runtime.h>
#include <math.h>

#define B_    512
#define V_    6890
#define J_    24
#define NB_   10
#define K_    207     // 9*(J-1)
#define KPAD  224     // slots 207..216 = betas x shapedirs, 217..223 zero
#define NCOL  20670   // V*3
#define TV    32      // verts per g1 block tile
#define TC    96      // cols per g1 block tile (TV*3)
#define CPAD  20736   // 216*96 = 108*192
#define NCVT  2268    // 324 * 7 cvt blocks
#define SPD_STRIDE 232   // s_pd k-stride in halves (224 + 8 pad)
#define VPL_STRIDE 200   // k_lbs LDS vp col stride in floats (192 + 8 pad)
#define VP_STRIDE  104   // fallback LDS vp stride

typedef __attribute__((ext_vector_type(8))) __bf16 bf16x8;
typedef __attribute__((ext_vector_type(4))) float  f32x4;

__constant__ int c_par[24] = {-1,0,0,0,1,2,3,4,5,6,7,8,9,9,9,12,13,14,16,17,18,19,20,21};
__constant__ int c_lev[24] = { 0,1,1,1,2,2,2,3,3,3,4,4,4,4,4, 5, 5, 5, 6, 6, 7, 7, 8, 8};

__device__ __forceinline__ unsigned short f2bf(float x) {
    union { float f; unsigned u; } v; v.f = x;
    unsigned r = (v.u + 0x7FFFu + ((v.u >> 16) & 1u)) >> 16;
    return (unsigned short)r;
}
__device__ __forceinline__ float bf2f(unsigned short h) {
    union { unsigned u; float f; } v; v.u = (unsigned)h << 16;
    return v.f;
}
__device__ __forceinline__ void wsync() {
    asm volatile("s_waitcnt lgkmcnt(0)" ::: "memory");
}

// ---------------------------------------------------------------------------
// K_PRE (fused): blocks [0, NCVT):      posedirs/shapedirs -> pdT bf16
//                blocks [NCVT,NCVT+72): JT/JS reduction
// ---------------------------------------------------------------------------
__global__ __launch_bounds__(256) void k_pre(const float* __restrict__ pd,
                                             const float* __restrict__ sd,
                                             const float* __restrict__ Jreg,
                                             const float* __restrict__ vt,
                                             unsigned short* __restrict__ pdT,
                                             float* __restrict__ JS,
                                             float* __restrict__ JT,
                                             int do_cvt)
{
    const int tid = threadIdx.x;
    const int bx  = blockIdx.x;

    if (bx < NCVT) {
        if (!do_cvt) return;
        const int c  = (bx % 324) * 64 + (tid & 63);
        const int kq = (bx / 324) * 4 + (tid >> 6);   // 0..27
        unsigned short u[8];
#pragma unroll
        for (int e = 0; e < 8; ++e) {
            const int k = kq * 8 + e;
            float x = 0.f;
            if (c < NCOL) {
                if (k < K_)            x = pd[(size_t)k * NCOL + c];
                else if (k < K_ + NB_) x = sd[(size_t)c * NB_ + (k - K_)];
            }
            u[e] = f2bf(x);
        }
        *reinterpret_cast<uint4*>(&pdT[(size_t)c * KPAD + kq * 8]) =
            *reinterpret_cast<const uint4*>(u);
        return;
    }

    // ---- jreg part ----
    const int jk = bx - NCVT;           // 0..71
    const int j = jk / 3, k = jk % 3;
    float acc[11];
#pragma unroll
    for (int i = 0; i < 11; ++i) acc[i] = 0.f;

#pragma unroll 4
    for (int v = tid; v < V_; v += 256) {
        const float r = Jreg[j * V_ + v];
        acc[0] = fmaf(r, vt[v * 3 + k], acc[0]);
        const float* s = &sd[(v * 3 + k) * NB_];
#pragma unroll
        for (int l = 0; l < NB_; ++l) acc[1 + l] = fmaf(r, s[l], acc[1 + l]);
    }

    __shared__ float red[4][11];
    const int lane = tid & 63, w = tid >> 6;
#pragma unroll
    for (int i = 0; i < 11; ++i) {
        float a = acc[i];
        for (int off = 32; off; off >>= 1) a += __shfl_xor(a, off, 64);
        acc[i] = a;
    }
    if (lane == 0) {
#pragma unroll
        for (int i = 0; i < 11; ++i) red[w][i] = acc[i];
    }
    __syncthreads();
    if (tid == 0) {
        for (int i = 0; i < 11; ++i) {
            const float s = red[0][i] + red[1][i] + red[2][i] + red[3][i];
            if (i == 0) JT[j * 3 + k] = s;
            else        JS[(j * 3 + k) * NB_ + (i - 1)] = s;
        }
    }
}

// ---------------------------------------------------------------------------
// K_POSE: joint pipeline, one wave per batch. grid = 128 x 256.
// ---------------------------------------------------------------------------
__global__ __launch_bounds__(256) void k_pose(const float* __restrict__ betas,
                                              const float* __restrict__ body_pose,
                                              const float* __restrict__ global_orient,
                                              const float* __restrict__ transl,
                                              const float* __restrict__ JS,
                                              const float* __restrict__ JT,
                                              unsigned short* __restrict__ Atout,
                                              unsigned short* __restrict__ pfout,
                                              float* __restrict__ joints_out)
{
    const int wv   = threadIdx.x >> 6;
    const int j    = threadIdx.x & 63;
    const int b    = blockIdx.x * 4 + wv;

    __shared__ float sR[4][24][9];
    __shared__ float sJ[4][24][3];
    __shared__ float sTl[4][24][12];
    __shared__ float sTg[4][24][12];

    if (j < 24) {
        float rx, ry, rz;
        if (j == 0) {
            rx = global_orient[b * 3 + 0];
            ry = global_orient[b * 3 + 1];
            rz = global_orient[b * 3 + 2];
        } else {
            const float* p = &body_pose[b * 69 + (j - 1) * 3];
            rx = p[0]; ry = p[1]; rz = p[2];
        }
        const float ax = rx + 1e-8f, ay = ry + 1e-8f, az = rz + 1e-8f;
        const float angle = sqrtf(ax * ax + ay * ay + az * az);
        const float inv = 1.f / angle;
        const float x = rx * inv, y = ry * inv, z = rz * inv;
        const float s = sinf(angle), c = cosf(angle), t = 1.f - c;

        float R[9];
        R[0] = 1.f - t * (y * y + z * z);
        R[1] = -s * z + t * x * y;
        R[2] =  s * y + t * x * z;
        R[3] =  s * z + t * x * y;
        R[4] = 1.f - t * (x * x + z * z);
        R[5] = -s * x + t * y * z;
        R[6] = -s * y + t * x * z;
        R[7] =  s * x + t * y * z;
        R[8] = 1.f - t * (x * x + y * y);

#pragma unroll
        for (int e = 0; e < 9; ++e) sR[wv][j][e] = R[e];

        if (j >= 1) {
#pragma unroll
            for (int e = 0; e < 9; ++e) {
                const float id = (e == 0 || e == 4 || e == 8) ? 1.f : 0.f;
                pfout[b * KPAD + (j - 1) * 9 + e] = f2bf(R[e] - id);
            }
        }
#pragma unroll
        for (int k = 0; k < 3; ++k) {
            float jr = JT[j * 3 + k];
#pragma unroll
            for (int l = 0; l < NB_; ++l)
                jr = fmaf(betas[b * NB_ + l], JS[(j * 3 + k) * NB_ + l], jr);
            sJ[wv][j][k] = jr;
        }
    }
    if (j < KPAD - K_) {
        const float val = (j < NB_) ? betas[b * NB_ + j] : 0.f;
        pfout[b * KPAD + K_ + j] = f2bf(val);
    }
    wsync();

    if (j < 24) {
        const int p = c_par[j];
        float t0 = sJ[wv][j][0], t1 = sJ[wv][j][1], t2 = sJ[wv][j][2];
        if (j > 0) { t0 -= sJ[wv][p][0]; t1 -= sJ[wv][p][1]; t2 -= sJ[wv][p][2]; }
        sTl[wv][j][0] = sR[wv][j][0]; sTl[wv][j][1] = sR[wv][j][1];
        sTl[wv][j][2] = sR[wv][j][2]; sTl[wv][j][3] = t0;
        sTl[wv][j][4] = sR[wv][j][3]; sTl[wv][j][5] = sR[wv][j][4];
        sTl[wv][j][6] = sR[wv][j][5]; sTl[wv][j][7] = t1;
        sTl[wv][j][8] = sR[wv][j][6]; sTl[wv][j][9] = sR[wv][j][7];
        sTl[wv][j][10] = sR[wv][j][8]; sTl[wv][j][11] = t2;
    }
    wsync();

    if (j == 0) {
#pragma unroll
        for (int e = 0; e < 12; ++e) sTg[wv][0][e] = sTl[wv][0][e];
    }
    wsync();

    for (int lev = 1; lev <= 8; ++lev) {
        if (j < 24 && c_lev[j] == lev) {
            const int p = c_par[j];
            float o[12];
#pragma unroll
            for (int r = 0; r < 3; ++r) {
#pragma unroll
                for (int c = 0; c < 4; ++c) {
                    float v = (c == 3) ? sTg[wv][p][r * 4 + 3] : 0.f;
#pragma unroll
                    for (int m = 0; m < 3; ++m)
                        v = fmaf(sTg[wv][p][r * 4 + m], sTl[wv][j][m * 4 + c], v);
                    o[r * 4 + c] = v;
                }
            }
#pragma unroll
            for (int e = 0; e < 12; ++e) sTg[wv][j][e] = o[e];
        }
        wsync();
    }

    if (j < 24) {
        float corr[3];
#pragma unroll
        for (int r = 0; r < 3; ++r)
            corr[r] = sTg[wv][j][r * 4 + 0] * sJ[wv][j][0]
                    + sTg[wv][j][r * 4 + 1] * sJ[wv][j][1]
                    + sTg[wv][j][r * 4 + 2] * sJ[wv][j][2];

#pragma unroll
        for (int r = 0; r < 3; ++r) {
            float row[4];
            row[0] = sTg[wv][j][r * 4 + 0];
            row[1] = sTg[wv][j][r * 4 + 1];
            row[2] = sTg[wv][j][r * 4 + 2];
            row[3] = sTg[wv][j][r * 4 + 3] - corr[r] + transl[b * 3 + r];
#pragma unroll
            for (int cc = 0; cc < 4; ++cc) {
                const float val = row[cc];
                const unsigned short hi = f2bf(val);
                const unsigned short lo = f2bf(val - bf2f(hi));
                const size_t base = ((size_t)b * 16 + r * 4 + cc) * 64;
                Atout[base + j]      = hi;
                Atout[base + 32 + j] = lo;
            }
        }
#pragma unroll
        for (int k = 0; k < 3; ++k)
            joints_out[(b * 24 + j) * 3 + k] = sTg[wv][j][k * 4 + 3] + transl[b * 3 + k];
    }
    for (int idx = j; idx < 1024; idx += 64) {
        const int e = idx >> 6, jj = idx & 63;
        if (e >= 12 || (jj & 31) >= 24)
            Atout[((size_t)b * 16 + e) * 64 + jj] = 0;
    }
}

// ---------------------------------------------------------------------------
// K_G1: pure GEMM1, 2 btiles per block (pdT staging amortized), DIRECT
// register stores. grid = 864 (216 vtiles x 4 bpairs, XCD-chunked), 4 waves.
// ---------------------------------------------------------------------------
__global__ __launch_bounds__(256, 3) void k_g1(
    const float* __restrict__ v_template,        // flat [NCOL]
    const unsigned short* __restrict__ pdT,      // bf16 [CPAD][KPAD]
    const unsigned short* __restrict__ pf,       // bf16 [B][KPAD]
    float* __restrict__ vp_ws)                   // f32 [B][CPAD]
{
    __shared__ __align__(16) unsigned short s_pd[TC * SPD_STRIDE];

    const int tid = threadIdx.x;
    const int wv  = tid >> 6;
    const int m   = tid & 15;
    const int g   = (tid & 63) >> 4;

    const int lraw  = blockIdx.x;                 // 864 % 8 == 0 -> bijective
    const int gl    = (lraw & 7) * 108 + (lraw >> 3);
    const int vtile = gl >> 2;                    // 0..215
    const int bpair = gl & 3;                     // 0..3 -> btiles {2p, 2p+1}
    const int vb3   = vtile * TC;

    // ---- stage full pdT tile: 96 cols x 224 k = 2688 uint4, all in flight ----
#pragma unroll
    for (int i = 0; i < 11; ++i) {
        const int idx = i * 256 + tid;
        if (i == 10 && tid >= 128) break;         // 2688 = 10*256 + 128
        const int col = idx / 28, kq = idx % 28;
        const uint4 val = *reinterpret_cast<const uint4*>(
            &pdT[(size_t)(vb3 + col) * KPAD + kq * 8]);
        *reinterpret_cast<uint4*>(&s_pd[col * SPD_STRIDE + kq * 8]) = val;
    }

    // ---- v_template row (reused by both btiles) ----
    float vtf[6];
#pragma unroll
    for (int nt = 0; nt < 6; ++nt) {
        const int c = vb3 + nt * 16 + m;
        vtf[nt] = (c < NCOL) ? v_template[c] : 0.f;
    }

    __syncthreads();

    // ---- 2 btiles: GEMM1 + direct store each ----
#pragma unroll 1
    for (int u = 0; u < 2; ++u) {
        const int bbase = (bpair * 2 + u) * 64;
        const int brow  = bbase + wv * 16 + m;

        bf16x8 af[7];
#pragma unroll
        for (int ck = 0; ck < 7; ++ck)
            af[ck] = *reinterpret_cast<const bf16x8*>(
                &pf[(size_t)brow * KPAD + ck * 32 + g * 8]);

        f32x4 acc1[6];
#pragma unroll
        for (int i = 0; i < 6; ++i) acc1[i] = (f32x4){0.f, 0.f, 0.f, 0.f};

#pragma unroll
        for (int ck = 0; ck < 7; ++ck) {
            const unsigned short* pb = &s_pd[m * SPD_STRIDE + ck * 32 + g * 8];
#pragma unroll
            for (int nt = 0; nt < 6; ++nt) {
                const bf16x8 bfr = *reinterpret_cast<const bf16x8*>(
                    &pb[nt * 16 * SPD_STRIDE]);
                acc1[nt] = __builtin_amdgcn_mfma_f32_16x16x32_bf16(af[ck], bfr, acc1[nt], 0, 0, 0);
            }
        }

        // direct store: lane(m,g) holds v_posed[b = bbase+wv*16+g*4+r][nt*16+m]
        const int b0 = bbase + wv * 16 + g * 4;
#pragma unroll
        for (int nt = 0; nt < 6; ++nt) {
#pragma unroll
            for (int r = 0; r < 4; ++r)
                vp_ws[(size_t)(b0 + r) * CPAD + vb3 + nt * 16 + m]
                    = acc1[nt][r] + vtf[nt];
        }
    }
}

// ---------------------------------------------------------------------------
// K_LBS: GEMM2 + combine, vp staged to LDS in ONE coalesced round trip.
// grid = 1728 (108 vtiles64 x 16 btiles32, XCD-chunked), block 256 (4 waves).
// LDS: s_vp [32][200] f32 = 25.6 KB + s_w [64][32] bf16 = 4 KB -> 5 blocks/CU.
// ---------------------------------------------------------------------------
__global__ __launch_bounds__(256, 5) void k_lbs(
    const float* __restrict__ lbs_weights,       // [V][24]
    const unsigned short* __restrict__ At,       // bf16 [B*16][64] hi|lo
    const float* __restrict__ vp_ws,             // f32 [B][CPAD]
    float* __restrict__ out)                     // [B][V][3]
{
    __shared__ __align__(16) float s_vp[32 * VPL_STRIDE];   // 25.6 KB
    __shared__ unsigned short s_w[64 * 32];                 // 4 KB

    const int tid = threadIdx.x;
    const int wv  = tid >> 6;
    const int m   = tid & 15;
    const int g   = (tid & 63) >> 4;

    const int lraw  = blockIdx.x;                 // 1728 % 8 == 0 -> bijective
    const int gl    = (lraw & 7) * 216 + (lraw >> 3);
    const int vtile = gl >> 4;                    // 0..107 (64 verts)
    const int btile = gl & 15;                    // 0..15  (32 batches)
    const int vbase = vtile * 64;
    const int bbase = btile * 32;
    const int vb3   = vtile * 192;

    // ---- stage vp tile [32 b][192 cols] = 1536 uint4 (32 rows x 48/row),
    //      6 x 256 threads, ALL loads in flight, one drain ----
#pragma unroll
    for (int it = 0; it < 6; ++it) {
        const int idx = it * 256 + tid;
        const int row = idx / 48, q = idx % 48;
        const uint4 val = *reinterpret_cast<const uint4*>(
            &vp_ws[(size_t)(bbase + row) * CPAD + vb3 + q * 4]);
        *reinterpret_cast<uint4*>(&s_vp[row * VPL_STRIDE + q * 4]) = val;
    }

    // ---- stage W: lbs_weights -> bf16 [64][32] ----
    {
        const int v  = tid >> 2, jq = tid & 3;
        const int vv = vbase + v;
        const int vc = vv < V_ ? vv : V_ - 1;
        unsigned short u[8];
        if (jq < 3) {
            const float* src = &lbs_weights[vc * 24 + jq * 8];
#pragma unroll
            for (int e = 0; e < 8; ++e) u[e] = f2bf(src[e]);
        } else {
#pragma unroll
            for (int e = 0; e < 8; ++e) u[e] = 0;
        }
        *reinterpret_cast<uint4*>(&s_w[v * 32 + jq * 8]) =
            *reinterpret_cast<const uint4*>(u);
    }
    __syncthreads();

    bf16x8 wf[4];
#pragma unroll
    for (int nt = 0; nt < 4; ++nt)
        wf[nt] = *reinterpret_cast<const bf16x8*>(&s_w[(nt * 16 + m) * 32 + g * 8]);

    // ---- 8 batches per wave, At prefetch depth-2 (static ring) ----
    const int b0 = bbase + wv * 8;
    bf16x8 phi[2], plo[2];
#pragma unroll
    for (int p = 0; p < 2; ++p) {
        const size_t arow = ((size_t)(b0 + p) * 16 + m) * 64;
        phi[p] = *reinterpret_cast<const bf16x8*>(&At[arow + g * 8]);
        plo[p] = *reinterpret_cast<const bf16x8*>(&At[arow + 32 + g * 8]);
    }

#pragma unroll
    for (int mt = 0; mt < 8; ++mt) {
        const bf16x8 ahi = phi[mt & 1], alo = plo[mt & 1];
        if (mt < 6) {
            const size_t arow = ((size_t)(b0 + mt + 2) * 16 + m) * 64;
            phi[mt & 1] = *reinterpret_cast<const bf16x8*>(&At[arow + g * 8]);
            plo[mt & 1] = *reinterpret_cast<const bf16x8*>(&At[arow + 32 + g * 8]);
        }
        const int b = b0 + mt;
        const float* vpb = &s_vp[(wv * 8 + mt) * VPL_STRIDE];
#pragma unroll
        for (int nt = 0; nt < 4; ++nt) {
            f32x4 t = (f32x4){0.f, 0.f, 0.f, 0.f};
            t = __builtin_amdgcn_mfma_f32_16x16x32_bf16(ahi, wf[nt], t, 0, 0, 0);
            t = __builtin_amdgcn_mfma_f32_16x16x32_bf16(alo, wf[nt], t, 0, 0, 0);
            const float vpx = vpb[nt * 48 + 3 * m + 0];   // 16 lanes stride-3,
            const float vpy = vpb[nt * 48 + 3 * m + 1];   // g-groups broadcast:
            const float vpz = vpb[nt * 48 + 3 * m + 2];   // conflict-free
            const float o = fmaf(t[0], vpx, fmaf(t[1], vpy, fmaf(t[2], vpz, t[3])));
            const int vv = vbase + nt * 16 + m;
            if (g < 3 && vv < V_)
                out[((size_t)b * V_ + vv) * 3 + g] = o;
        }
    }
}

// ---------------------------------------------------------------------------
// Fallback fused kernel (round-7 structure, f32-source staging) for small ws.
// ---------------------------------------------------------------------------
__global__ __launch_bounds__(256, 3) void k_fused_fb(
    const float* __restrict__ v_template,
    const float* __restrict__ posedirs,
    const float* __restrict__ shapedirs,
    const float* __restrict__ lbs_weights,
    const unsigned short* __restrict__ pf,
    const unsigned short* __restrict__ At,
    float* __restrict__ out)
{
    __shared__ __align__(16) char smem[44544 + 2048];
    unsigned short* s_pd = (unsigned short*)smem;
    unsigned short* s_w  = (unsigned short*)(smem + 44544);
    float*          s_vp = (float*)smem;

    const int tid = threadIdx.x;
    const int l   = tid & 63;
    const int wv  = tid >> 6;
    const int m   = l & 15;
    const int g   = l >> 4;

    const int lraw  = blockIdx.x;
    const int gl    = (lraw & 7) * 216 + (lraw >> 3);
    const int vtile = gl >> 3;
    const int btile = gl & 7;
    const int vbase = vtile * TV;
    const int bbase = btile * 64;
    const int vb3   = vtile * TC;

    if (tid < 128) {
        const int v  = tid >> 2, jq = tid & 3;
        const int vv = vbase + v;
        const int vc = vv < V_ ? vv : V_ - 1;
        unsigned short u[8];
        if (jq < 3) {
            const float* src = &lbs_weights[vc * 24 + jq * 8];
#pragma unroll
            for (int e = 0; e < 8; ++e) u[e] = f2bf(src[e]);
        } else {
#pragma unroll
            for (int e = 0; e < 8; ++e) u[e] = 0;
        }
        *reinterpret_cast<uint4*>(&s_w[v * 32 + jq * 8]) =
            *reinterpret_cast<const uint4*>(u);
    }

#pragma unroll
    for (int i = 0; i < 11; ++i) {
        const int idx = i * 256 + tid;
        if (i == 10 && tid >= 128) break;
        const int col = idx / 28, kq = idx % 28;
        unsigned short u[8];
        const int c = vb3 + col;
#pragma unroll
        for (int e = 0; e < 8; ++e) {
            const int k = kq * 8 + e;
            float x = 0.f;
            if (c < NCOL) {
                if (k < K_)            x = posedirs[(size_t)k * NCOL + c];
                else if (k < K_ + NB_) x = shapedirs[(size_t)c * NB_ + (k - K_)];
            }
            u[e] = f2bf(x);
        }
        *reinterpret_cast<uint4*>(&s_pd[col * SPD_STRIDE + kq * 8]) =
            *reinterpret_cast<const uint4*>(u);
    }

    bf16x8 af[7];
#pragma unroll
    for (int ck = 0; ck < 7; ++ck)
        af[ck] = *reinterpret_cast<const bf16x8*>(
            &pf[(size_t)(bbase + wv * 16 + m) * KPAD + ck * 32 + g * 8]);

    __syncthreads();

    f32x4 acc1[6];
#pragma unroll
    for (int i = 0; i < 6; ++i) acc1[i] = (f32x4){0.f, 0.f, 0.f, 0.f};
#pragma unroll
    for (int ck = 0; ck < 7; ++ck) {
        const unsigned short* pb = &s_pd[m * SPD_STRIDE + ck * 32 + g * 8];
#pragma unroll
        for (int nt = 0; nt < 6; ++nt) {
            const bf16x8 bfr = *reinterpret_cast<const bf16x8*>(&pb[nt * 16 * SPD_STRIDE]);
            acc1[nt] = __builtin_amdgcn_mfma_f32_16x16x32_bf16(af[ck], bfr, acc1[nt], 0, 0, 0);
        }
    }
    __syncthreads();

    float* vp = &s_vp[wv * 16 * VP_STRIDE];
#pragma unroll
    for (int nt = 0; nt < 6; ++nt) {
        const int c = vb3 + nt * 16 + m;
        const float vtf = (c < NCOL) ? v_template[c] : 0.f;
#pragma unroll
        for (int r = 0; r < 4; ++r)
            vp[(g * 4 + r) * VP_STRIDE + nt * 16 + m] = acc1[nt][r] + vtf;
    }
    wsync();

    bf16x8 wf[2];
#pragma unroll
    for (int nt = 0; nt < 2; ++nt)
        wf[nt] = *reinterpret_cast<const bf16x8*>(&s_w[(nt * 16 + m) * 32 + g * 8]);

    const int b0 = bbase + wv * 16;
    bf16x8 phi[2], plo[2];
#pragma unroll
    for (int p = 0; p < 2; ++p) {
        const size_t arow = ((size_t)(b0 + p) * 16 + m) * 64;
        phi[p] = *reinterpret_cast<const bf16x8*>(&At[arow + g * 8]);
        plo[p] = *reinterpret_cast<const bf16x8*>(&At[arow + 32 + g * 8]);
    }
#pragma unroll
    for (int mt8 = 0; mt8 < 16; ++mt8) {
        const bf16x8 ahi = phi[mt8 & 1], alo = plo[mt8 & 1];
        if (mt8 < 14) {
            const size_t arow = ((size_t)(b0 + mt8 + 2) * 16 + m) * 64;
            phi[mt8 & 1] = *reinterpret_cast<const bf16x8*>(&At[arow + g * 8]);
            plo[mt8 & 1] = *reinterpret_cast<const bf16x8*>(&At[arow + 32 + g * 8]);
        }
        const int b = b0 + mt8;
#pragma unroll
        for (int nt = 0; nt < 2; ++nt) {
            f32x4 t = (f32x4){0.f, 0.f, 0.f, 0.f};
            t = __builtin_amdgcn_mfma_f32_16x16x32_bf16(ahi, wf[nt], t, 0, 0, 0);
            t = __builtin_amdgcn_mfma_f32_16x16x32_bf16(alo, wf[nt], t, 0, 0, 0);
            const float vpx = vp[mt8 * VP_STRIDE + nt * 48 + 3 * m + 0];
            const float vpy = vp[mt8 * VP_STRIDE + nt * 48 + 3 * m + 1];
            const float vpz = vp[mt8 * VP_STRIDE + nt * 48 + 3 * m + 2];
            const float o = fmaf(t[0], vpx, fmaf(t[1], vpy, fmaf(t[2], vpz, t[3])));
            const int vv = vbase + nt * 16 + m;
            if (g < 3 && vv < V_)
                out[((size_t)b * V_ + vv) * 3 + g] = o;
        }
    }
}

// ---------------------------------------------------------------------------
extern "C" void kernel_launch(void* const* d_in, const int* in_sizes, int n_in,
                              void* d_out, int out_size, void* d_ws, size_t ws_size,
                              hipStream_t stream)
{
    const float* betas         = (const float*)d_in[0];
    const float* body_pose     = (const float*)d_in[1];
    const float* global_orient = (const float*)d_in[2];
    const float* transl        = (const float*)d_in[3];
    const float* v_template    = (const float*)d_in[4];
    const float* shapedirs     = (const float*)d_in[5];
    const float* posedirs      = (const float*)d_in[6];
    const float* J_regressor   = (const float*)d_in[7];
    const float* lbs_weights   = (const float*)d_in[8];

    float* out = (float*)d_out;
    float* ws  = (float*)d_ws;

    // ws layout: JS[720] JT[72] f32 | pf bf16 [512*224] | At bf16 [8192*64]
    //            | pdT bf16 [CPAD*224] | vp f32 [512*CPAD]
    float* JS = ws;
    float* JT = ws + 720;
    unsigned short* pfw = (unsigned short*)(ws + 792);
    unsigned short* Atw = pfw + (size_t)B_ * KPAD;
    unsigned short* pdT = Atw + (size_t)B_ * 16 * 64;
    float* vpw = (float*)(pdT + (size_t)CPAD * KPAD);

    const size_t needed = 792u * 4 + (size_t)B_ * KPAD * 2
                        + (size_t)B_ * 16 * 64 * 2
                        + (size_t)CPAD * KPAD * 2
                        + (size_t)B_ * CPAD * 4;         // ~53.0 MB
    const bool pre = (ws_size >= needed);

    float* joints = out + (size_t)B_ * V_ * 3;

    k_pre <<<NCVT + 72, 256, 0, stream>>>(posedirs, shapedirs, J_regressor,
                                          v_template, pdT, JS, JT, pre ? 1 : 0);
    k_pose<<<B_ / 4, 256, 0, stream>>>(betas, body_pose, global_orient, transl,
                                       JS, JT, Atw, pfw, joints);
    if (pre) {
        k_g1 <<<864,  256, 0, stream>>>(v_template, pdT, pfw, vpw);
        k_lbs<<<1728, 256, 0, stream>>>(lbs_weights, Atw, vpw, out);
    } else {
        k_fused_fb<<<1728, 256, 0, stream>>>(v_template, posedirs, shapedirs,
                                             lbs_weights, pfw, Atw, out);
    }
}

// Round 11
// 73.354 us; speedup vs baseline: 1.2719x; 1.2719x over previous
//
#include <hip/hip_runtime.h>
#include <math.h>

#define B_    512
#define V_    6890
#define J_    24
#define NB_   10
#define K_    207     // 9*(J-1)
#define KPAD  224     // slots 207..216 = betas x shapedirs, 217..223 zero
#define NCOL  20670   // V*3
#define TV    32      // verts per g1 block tile
#define TC    96      // cols per g1 block tile (TV*3)
#define CPAD  20736   // 216*96 = 108*192
#define NCVT  2268    // 324 * 7 cvt blocks
#define SPD_STRIDE 232   // s_pd k-stride in halves (224 + 8 pad)
#define VPL_STRIDE 200   // k_lbs LDS vp col stride in floats (192 + 8 pad)
#define VP_STRIDE  104   // g1/fallback LDS vp stride (96 + 8, 16B-aligned rows)

typedef __attribute__((ext_vector_type(8))) __bf16 bf16x8;
typedef __attribute__((ext_vector_type(4))) float  f32x4;

__constant__ int c_par[24] = {-1,0,0,0,1,2,3,4,5,6,7,8,9,9,9,12,13,14,16,17,18,19,20,21};
__constant__ int c_lev[24] = { 0,1,1,1,2,2,2,3,3,3,4,4,4,4,4, 5, 5, 5, 6, 6, 7, 7, 8, 8};

__device__ __forceinline__ unsigned short f2bf(float x) {
    union { float f; unsigned u; } v; v.f = x;
    unsigned r = (v.u + 0x7FFFu + ((v.u >> 16) & 1u)) >> 16;
    return (unsigned short)r;
}
__device__ __forceinline__ float bf2f(unsigned short h) {
    union { unsigned u; float f; } v; v.u = (unsigned)h << 16;
    return v.f;
}
__device__ __forceinline__ void wsync() {
    asm volatile("s_waitcnt lgkmcnt(0)" ::: "memory");
}

// ---------------------------------------------------------------------------
// K_PRE (fused): blocks [0, NCVT):      posedirs/shapedirs -> pdT bf16
//                blocks [NCVT,NCVT+72): JT/JS reduction
// ---------------------------------------------------------------------------
__global__ __launch_bounds__(256) void k_pre(const float* __restrict__ pd,
                                             const float* __restrict__ sd,
                                             const float* __restrict__ Jreg,
                                             const float* __restrict__ vt,
                                             unsigned short* __restrict__ pdT,
                                             float* __restrict__ JS,
                                             float* __restrict__ JT,
                                             int do_cvt)
{
    const int tid = threadIdx.x;
    const int bx  = blockIdx.x;

    if (bx < NCVT) {
        if (!do_cvt) return;
        const int c  = (bx % 324) * 64 + (tid & 63);
        const int kq = (bx / 324) * 4 + (tid >> 6);   // 0..27
        unsigned short u[8];
#pragma unroll
        for (int e = 0; e < 8; ++e) {
            const int k = kq * 8 + e;
            float x = 0.f;
            if (c < NCOL) {
                if (k < K_)            x = pd[(size_t)k * NCOL + c];
                else if (k < K_ + NB_) x = sd[(size_t)c * NB_ + (k - K_)];
            }
            u[e] = f2bf(x);
        }
        *reinterpret_cast<uint4*>(&pdT[(size_t)c * KPAD + kq * 8]) =
            *reinterpret_cast<const uint4*>(u);
        return;
    }

    // ---- jreg part ----
    const int jk = bx - NCVT;           // 0..71
    const int j = jk / 3, k = jk % 3;
    float acc[11];
#pragma unroll
    for (int i = 0; i < 11; ++i) acc[i] = 0.f;

#pragma unroll 4
    for (int v = tid; v < V_; v += 256) {
        const float r = Jreg[j * V_ + v];
        acc[0] = fmaf(r, vt[v * 3 + k], acc[0]);
        const float* s = &sd[(v * 3 + k) * NB_];
#pragma unroll
        for (int l = 0; l < NB_; ++l) acc[1 + l] = fmaf(r, s[l], acc[1 + l]);
    }

    __shared__ float red[4][11];
    const int lane = tid & 63, w = tid >> 6;
#pragma unroll
    for (int i = 0; i < 11; ++i) {
        float a = acc[i];
        for (int off = 32; off; off >>= 1) a += __shfl_xor(a, off, 64);
        acc[i] = a;
    }
    if (lane == 0) {
#pragma unroll
        for (int i = 0; i < 11; ++i) red[w][i] = acc[i];
    }
    __syncthreads();
    if (tid == 0) {
        for (int i = 0; i < 11; ++i) {
            const float s = red[0][i] + red[1][i] + red[2][i] + red[3][i];
            if (i == 0) JT[j * 3 + k] = s;
            else        JS[(j * 3 + k) * NB_ + (i - 1)] = s;
        }
    }
}

// ---------------------------------------------------------------------------
// K_POSE: joint pipeline, one wave per batch. grid = 128 x 256.
// ---------------------------------------------------------------------------
__global__ __launch_bounds__(256) void k_pose(const float* __restrict__ betas,
                                              const float* __restrict__ body_pose,
                                              const float* __restrict__ global_orient,
                                              const float* __restrict__ transl,
                                              const float* __restrict__ JS,
                                              const float* __restrict__ JT,
                                              unsigned short* __restrict__ Atout,
                                              unsigned short* __restrict__ pfout,
                                              float* __restrict__ joints_out)
{
    const int wv   = threadIdx.x >> 6;
    const int j    = threadIdx.x & 63;
    const int b    = blockIdx.x * 4 + wv;

    __shared__ float sR[4][24][9];
    __shared__ float sJ[4][24][3];
    __shared__ float sTl[4][24][12];
    __shared__ float sTg[4][24][12];

    if (j < 24) {
        float rx, ry, rz;
        if (j == 0) {
            rx = global_orient[b * 3 + 0];
            ry = global_orient[b * 3 + 1];
            rz = global_orient[b * 3 + 2];
        } else {
            const float* p = &body_pose[b * 69 + (j - 1) * 3];
            rx = p[0]; ry = p[1]; rz = p[2];
        }
        const float ax = rx + 1e-8f, ay = ry + 1e-8f, az = rz + 1e-8f;
        const float angle = sqrtf(ax * ax + ay * ay + az * az);
        const float inv = 1.f / angle;
        const float x = rx * inv, y = ry * inv, z = rz * inv;
        const float s = sinf(angle), c = cosf(angle), t = 1.f - c;

        float R[9];
        R[0] = 1.f - t * (y * y + z * z);
        R[1] = -s * z + t * x * y;
        R[2] =  s * y + t * x * z;
        R[3] =  s * z + t * x * y;
        R[4] = 1.f - t * (x * x + z * z);
        R[5] = -s * x + t * y * z;
        R[6] = -s * y + t * x * z;
        R[7] =  s * x + t * y * z;
        R[8] = 1.f - t * (x * x + y * y);

#pragma unroll
        for (int e = 0; e < 9; ++e) sR[wv][j][e] = R[e];

        if (j >= 1) {
#pragma unroll
            for (int e = 0; e < 9; ++e) {
                const float id = (e == 0 || e == 4 || e == 8) ? 1.f : 0.f;
                pfout[b * KPAD + (j - 1) * 9 + e] = f2bf(R[e] - id);
            }
        }
#pragma unroll
        for (int k = 0; k < 3; ++k) {
            float jr = JT[j * 3 + k];
#pragma unroll
            for (int l = 0; l < NB_; ++l)
                jr = fmaf(betas[b * NB_ + l], JS[(j * 3 + k) * NB_ + l], jr);
            sJ[wv][j][k] = jr;
        }
    }
    if (j < KPAD - K_) {
        const float val = (j < NB_) ? betas[b * NB_ + j] : 0.f;
        pfout[b * KPAD + K_ + j] = f2bf(val);
    }
    wsync();

    if (j < 24) {
        const int p = c_par[j];
        float t0 = sJ[wv][j][0], t1 = sJ[wv][j][1], t2 = sJ[wv][j][2];
        if (j > 0) { t0 -= sJ[wv][p][0]; t1 -= sJ[wv][p][1]; t2 -= sJ[wv][p][2]; }
        sTl[wv][j][0] = sR[wv][j][0]; sTl[wv][j][1] = sR[wv][j][1];
        sTl[wv][j][2] = sR[wv][j][2]; sTl[wv][j][3] = t0;
        sTl[wv][j][4] = sR[wv][j][3]; sTl[wv][j][5] = sR[wv][j][4];
        sTl[wv][j][6] = sR[wv][j][5]; sTl[wv][j][7] = t1;
        sTl[wv][j][8] = sR[wv][j][6]; sTl[wv][j][9] = sR[wv][j][7];
        sTl[wv][j][10] = sR[wv][j][8]; sTl[wv][j][11] = t2;
    }
    wsync();

    if (j == 0) {
#pragma unroll
        for (int e = 0; e < 12; ++e) sTg[wv][0][e] = sTl[wv][0][e];
    }
    wsync();

    for (int lev = 1; lev <= 8; ++lev) {
        if (j < 24 && c_lev[j] == lev) {
            const int p = c_par[j];
            float o[12];
#pragma unroll
            for (int r = 0; r < 3; ++r) {
#pragma unroll
                for (int c = 0; c < 4; ++c) {
                    float v = (c == 3) ? sTg[wv][p][r * 4 + 3] : 0.f;
#pragma unroll
                    for (int m = 0; m < 3; ++m)
                        v = fmaf(sTg[wv][p][r * 4 + m], sTl[wv][j][m * 4 + c], v);
                    o[r * 4 + c] = v;
                }
            }
#pragma unroll
            for (int e = 0; e < 12; ++e) sTg[wv][j][e] = o[e];
        }
        wsync();
    }

    if (j < 24) {
        float corr[3];
#pragma unroll
        for (int r = 0; r < 3; ++r)
            corr[r] = sTg[wv][j][r * 4 + 0] * sJ[wv][j][0]
                    + sTg[wv][j][r * 4 + 1] * sJ[wv][j][1]
                    + sTg[wv][j][r * 4 + 2] * sJ[wv][j][2];

#pragma unroll
        for (int r = 0; r < 3; ++r) {
            float row[4];
            row[0] = sTg[wv][j][r * 4 + 0];
            row[1] = sTg[wv][j][r * 4 + 1];
            row[2] = sTg[wv][j][r * 4 + 2];
            row[3] = sTg[wv][j][r * 4 + 3] - corr[r] + transl[b * 3 + r];
#pragma unroll
            for (int cc = 0; cc < 4; ++cc) {
                const float val = row[cc];
                const unsigned short hi = f2bf(val);
                const unsigned short lo = f2bf(val - bf2f(hi));
                const size_t base = ((size_t)b * 16 + r * 4 + cc) * 64;
                Atout[base + j]      = hi;
                Atout[base + 32 + j] = lo;
            }
        }
#pragma unroll
        for (int k = 0; k < 3; ++k)
            joints_out[(b * 24 + j) * 3 + k] = sTg[wv][j][k * 4 + 3] + transl[b * 3 + k];
    }
    for (int idx = j; idx < 1024; idx += 64) {
        const int e = idx >> 6, jj = idx & 63;
        if (e >= 12 || (jj & 31) >= 24)
            Atout[((size_t)b * 16 + e) * 64 + jj] = 0;
    }
}

// ---------------------------------------------------------------------------
// K_G1: pure GEMM1 (round-8 proven structure). v_posed = pf @ pdT^T + vt,
// written f32 via LDS transpose + fully-coalesced uint4 stores (1 KB/instr —
// no partial-line RFO/write-amplification).
// grid = 1728 (216 vtiles x 8 btiles, XCD-chunked), block 256 (4 waves).
// LDS: s_pd [96][232] bf16 = 44544 B (vp alias [4][16][104] f32 = 26.6 KB).
// ---------------------------------------------------------------------------
__global__ __launch_bounds__(256, 3) void k_g1(
    const float* __restrict__ v_template,        // flat [NCOL]
    const unsigned short* __restrict__ pdT,      // bf16 [CPAD][KPAD]
    const unsigned short* __restrict__ pf,       // bf16 [B][KPAD]
    float* __restrict__ vp_ws)                   // f32 [B][CPAD]
{
    __shared__ __align__(16) char smem[44544];
    unsigned short* s_pd = (unsigned short*)smem;
    float*          s_vp = (float*)smem;         // alias after barrier

    const int tid = threadIdx.x;
    const int l   = tid & 63;
    const int wv  = tid >> 6;
    const int m   = l & 15;
    const int g   = l >> 4;

    const int lraw  = blockIdx.x;                 // 1728 % 8 == 0 -> bijective
    const int gl    = (lraw & 7) * 216 + (lraw >> 3);
    const int vtile = gl >> 3;                    // 0..215
    const int btile = gl & 7;                     // 0..7
    const int bbase = btile * 64;
    const int vb3   = vtile * TC;

    // ---- stage full pdT tile: 96 cols x 224 k = 2688 uint4, all in flight ----
#pragma unroll
    for (int i = 0; i < 11; ++i) {
        const int idx = i * 256 + tid;
        if (i == 10 && tid >= 128) break;         // 2688 = 10*256 + 128
        const int col = idx / 28, kq = idx % 28;
        const uint4 val = *reinterpret_cast<const uint4*>(
            &pdT[(size_t)(vb3 + col) * KPAD + kq * 8]);
        *reinterpret_cast<uint4*>(&s_pd[col * SPD_STRIDE + kq * 8]) = val;
    }

    // ---- prefetch all 7 A-frags while staging drains ----
    bf16x8 af[7];
#pragma unroll
    for (int ck = 0; ck < 7; ++ck)
        af[ck] = *reinterpret_cast<const bf16x8*>(
            &pf[(size_t)(bbase + wv * 16 + m) * KPAD + ck * 32 + g * 8]);

    __syncthreads();

    // ---- GEMM1: 42 ds_read + 42 MFMA ----
    f32x4 acc1[6];
#pragma unroll
    for (int i = 0; i < 6; ++i) acc1[i] = (f32x4){0.f, 0.f, 0.f, 0.f};

#pragma unroll
    for (int ck = 0; ck < 7; ++ck) {
        const unsigned short* pb = &s_pd[m * SPD_STRIDE + ck * 32 + g * 8];
#pragma unroll
        for (int nt = 0; nt < 6; ++nt) {
            const bf16x8 bfr = *reinterpret_cast<const bf16x8*>(
                &pb[nt * 16 * SPD_STRIDE]);
            acc1[nt] = __builtin_amdgcn_mfma_f32_16x16x32_bf16(af[ck], bfr, acc1[nt], 0, 0, 0);
        }
    }

    __syncthreads();   // all waves done reading s_pd before alias overwrite

    // ---- dump to per-wave LDS [16][104] (+v_template) ----
    float* vp = &s_vp[wv * 16 * VP_STRIDE];
#pragma unroll
    for (int nt = 0; nt < 6; ++nt) {
        const int c = vb3 + nt * 16 + m;
        const float vtf = (c < NCOL) ? v_template[c] : 0.f;
#pragma unroll
        for (int r = 0; r < 4; ++r)
            vp[(g * 4 + r) * VP_STRIDE + nt * 16 + m] = acc1[nt][r] + vtf;
    }
    wsync();           // wave-private region

    // ---- coalesced store: 16 rows x 24 uint4 per wave (1 KB/instruction) ----
    const int b0 = bbase + wv * 16;
#pragma unroll
    for (int i = 0; i < 6; ++i) {
        const int idx = i * 64 + l;
        const int rb = idx / 24, q = idx % 24;
        const uint4 val = *reinterpret_cast<const uint4*>(&vp[rb * VP_STRIDE + q * 4]);
        *reinterpret_cast<uint4*>(&vp_ws[(size_t)(b0 + rb) * CPAD + vb3 + q * 4]) = val;
    }
}

// ---------------------------------------------------------------------------
// K_LBS: GEMM2 + combine, vp staged to LDS in ONE coalesced round trip.
// grid = 1728 (108 vtiles64 x 16 btiles32, XCD-chunked), block 256 (4 waves).
// LDS: s_vp [32][200] f32 = 25.6 KB + s_w [64][32] bf16 = 4 KB -> 5 blocks/CU.
// ---------------------------------------------------------------------------
__global__ __launch_bounds__(256, 5) void k_lbs(
    const float* __restrict__ lbs_weights,       // [V][24]
    const unsigned short* __restrict__ At,       // bf16 [B*16][64] hi|lo
    const float* __restrict__ vp_ws,             // f32 [B][CPAD]
    float* __restrict__ out)                     // [B][V][3]
{
    __shared__ __align__(16) float s_vp[32 * VPL_STRIDE];   // 25.6 KB
    __shared__ unsigned short s_w[64 * 32];                 // 4 KB

    const int tid = threadIdx.x;
    const int wv  = tid >> 6;
    const int m   = tid & 15;
    const int g   = (tid & 63) >> 4;

    const int lraw  = blockIdx.x;                 // 1728 % 8 == 0 -> bijective
    const int gl    = (lraw & 7) * 216 + (lraw >> 3);
    const int vtile = gl >> 4;                    // 0..107 (64 verts)
    const int btile = gl & 15;                    // 0..15  (32 batches)
    const int vbase = vtile * 64;
    const int bbase = btile * 32;
    const int vb3   = vtile * 192;

    // ---- stage vp tile [32 b][192 cols] = 1536 uint4, 6 x 256 threads,
    //      all loads in flight, one drain ----
#pragma unroll
    for (int it = 0; it < 6; ++it) {
        const int idx = it * 256 + tid;
        const int row = idx / 48, q = idx % 48;
        const uint4 val = *reinterpret_cast<const uint4*>(
            &vp_ws[(size_t)(bbase + row) * CPAD + vb3 + q * 4]);
        *reinterpret_cast<uint4*>(&s_vp[row * VPL_STRIDE + q * 4]) = val;
    }

    // ---- stage W: lbs_weights -> bf16 [64][32] ----
    {
        const int v  = tid >> 2, jq = tid & 3;
        const int vv = vbase + v;
        const int vc = vv < V_ ? vv : V_ - 1;
        unsigned short u[8];
        if (jq < 3) {
            const float* src = &lbs_weights[vc * 24 + jq * 8];
#pragma unroll
            for (int e = 0; e < 8; ++e) u[e] = f2bf(src[e]);
        } else {
#pragma unroll
            for (int e = 0; e < 8; ++e) u[e] = 0;
        }
        *reinterpret_cast<uint4*>(&s_w[v * 32 + jq * 8]) =
            *reinterpret_cast<const uint4*>(u);
    }
    __syncthreads();

    bf16x8 wf[4];
#pragma unroll
    for (int nt = 0; nt < 4; ++nt)
        wf[nt] = *reinterpret_cast<const bf16x8*>(&s_w[(nt * 16 + m) * 32 + g * 8]);

    // ---- 8 batches per wave, At prefetch depth-2 (static ring) ----
    const int b0 = bbase + wv * 8;
    bf16x8 phi[2], plo[2];
#pragma unroll
    for (int p = 0; p < 2; ++p) {
        const size_t arow = ((size_t)(b0 + p) * 16 + m) * 64;
        phi[p] = *reinterpret_cast<const bf16x8*>(&At[arow + g * 8]);
        plo[p] = *reinterpret_cast<const bf16x8*>(&At[arow + 32 + g * 8]);
    }

#pragma unroll
    for (int mt = 0; mt < 8; ++mt) {
        const bf16x8 ahi = phi[mt & 1], alo = plo[mt & 1];
        if (mt < 6) {
            const size_t arow = ((size_t)(b0 + mt + 2) * 16 + m) * 64;
            phi[mt & 1] = *reinterpret_cast<const bf16x8*>(&At[arow + g * 8]);
            plo[mt & 1] = *reinterpret_cast<const bf16x8*>(&At[arow + 32 + g * 8]);
        }
        const int b = b0 + mt;
        const float* vpb = &s_vp[(wv * 8 + mt) * VPL_STRIDE];
#pragma unroll
        for (int nt = 0; nt < 4; ++nt) {
            f32x4 t = (f32x4){0.f, 0.f, 0.f, 0.f};
            t = __builtin_amdgcn_mfma_f32_16x16x32_bf16(ahi, wf[nt], t, 0, 0, 0);
            t = __builtin_amdgcn_mfma_f32_16x16x32_bf16(alo, wf[nt], t, 0, 0, 0);
            const float vpx = vpb[nt * 48 + 3 * m + 0];   // 16 lanes stride-3,
            const float vpy = vpb[nt * 48 + 3 * m + 1];   // g-groups broadcast:
            const float vpz = vpb[nt * 48 + 3 * m + 2];   // conflict-free
            const float o = fmaf(t[0], vpx, fmaf(t[1], vpy, fmaf(t[2], vpz, t[3])));
            const int vv = vbase + nt * 16 + m;
            if (g < 3 && vv < V_)
                out[((size_t)b * V_ + vv) * 3 + g] = o;
        }
    }
}

// ---------------------------------------------------------------------------
// Fallback fused kernel (round-7 structure, f32-source staging) for small ws.
// ---------------------------------------------------------------------------
__global__ __launch_bounds__(256, 3) void k_fused_fb(
    const float* __restrict__ v_template,
    const float* __restrict__ posedirs,
    const float* __restrict__ shapedirs,
    const float* __restrict__ lbs_weights,
    const unsigned short* __restrict__ pf,
    const unsigned short* __restrict__ At,
    float* __restrict__ out)
{
    __shared__ __align__(16) char smem[44544 + 2048];
    unsigned short* s_pd = (unsigned short*)smem;
    unsigned short* s_w  = (unsigned short*)(smem + 44544);
    float*          s_vp = (float*)smem;

    const int tid = threadIdx.x;
    const int l   = tid & 63;
    const int wv  = tid >> 6;
    const int m   = l & 15;
    const int g   = l >> 4;

    const int lraw  = blockIdx.x;
    const int gl    = (lraw & 7) * 216 + (lraw >> 3);
    const int vtile = gl >> 3;
    const int btile = gl & 7;
    const int vbase = vtile * TV;
    const int bbase = btile * 64;
    const int vb3   = vtile * TC;

    if (tid < 128) {
        const int v  = tid >> 2, jq = tid & 3;
        const int vv = vbase + v;
        const int vc = vv < V_ ? vv : V_ - 1;
        unsigned short u[8];
        if (jq < 3) {
            const float* src = &lbs_weights[vc * 24 + jq * 8];
#pragma unroll
            for (int e = 0; e < 8; ++e) u[e] = f2bf(src[e]);
        } else {
#pragma unroll
            for (int e = 0; e < 8; ++e) u[e] = 0;
        }
        *reinterpret_cast<uint4*>(&s_w[v * 32 + jq * 8]) =
            *reinterpret_cast<const uint4*>(u);
    }

#pragma unroll
    for (int i = 0; i < 11; ++i) {
        const int idx = i * 256 + tid;
        if (i == 10 && tid >= 128) break;
        const int col = idx / 28, kq = idx % 28;
        unsigned short u[8];
        const int c = vb3 + col;
#pragma unroll
        for (int e = 0; e < 8; ++e) {
            const int k = kq * 8 + e;
            float x = 0.f;
            if (c < NCOL) {
                if (k < K_)            x = posedirs[(size_t)k * NCOL + c];
                else if (k < K_ + NB_) x = shapedirs[(size_t)c * NB_ + (k - K_)];
            }
            u[e] = f2bf(x);
        }
        *reinterpret_cast<uint4*>(&s_pd[col * SPD_STRIDE + kq * 8]) =
            *reinterpret_cast<const uint4*>(u);
    }

    bf16x8 af[7];
#pragma unroll
    for (int ck = 0; ck < 7; ++ck)
        af[ck] = *reinterpret_cast<const bf16x8*>(
            &pf[(size_t)(bbase + wv * 16 + m) * KPAD + ck * 32 + g * 8]);

    __syncthreads();

    f32x4 acc1[6];
#pragma unroll
    for (int i = 0; i < 6; ++i) acc1[i] = (f32x4){0.f, 0.f, 0.f, 0.f};
#pragma unroll
    for (int ck = 0; ck < 7; ++ck) {
        const unsigned short* pb = &s_pd[m * SPD_STRIDE + ck * 32 + g * 8];
#pragma unroll
        for (int nt = 0; nt < 6; ++nt) {
            const bf16x8 bfr = *reinterpret_cast<const bf16x8*>(&pb[nt * 16 * SPD_STRIDE]);
            acc1[nt] = __builtin_amdgcn_mfma_f32_16x16x32_bf16(af[ck], bfr, acc1[nt], 0, 0, 0);
        }
    }
    __syncthreads();

    float* vp = &s_vp[wv * 16 * VP_STRIDE];
#pragma unroll
    for (int nt = 0; nt < 6; ++nt) {
        const int c = vb3 + nt * 16 + m;
        const float vtf = (c < NCOL) ? v_template[c] : 0.f;
#pragma unroll
        for (int r = 0; r < 4; ++r)
            vp[(g * 4 + r) * VP_STRIDE + nt * 16 + m] = acc1[nt][r] + vtf;
    }
    wsync();

    bf16x8 wf[2];
#pragma unroll
    for (int nt = 0; nt < 2; ++nt)
        wf[nt] = *reinterpret_cast<const bf16x8*>(&s_w[(nt * 16 + m) * 32 + g * 8]);

    const int b0 = bbase + wv * 16;
    bf16x8 phi[2], plo[2];
#pragma unroll
    for (int p = 0; p < 2; ++p) {
        const size_t arow = ((size_t)(b0 + p) * 16 + m) * 64;
        phi[p] = *reinterpret_cast<const bf16x8*>(&At[arow + g * 8]);
        plo[p] = *reinterpret_cast<const bf16x8*>(&At[arow + 32 + g * 8]);
    }
#pragma unroll
    for (int mt8 = 0; mt8 < 16; ++mt8) {
        const bf16x8 ahi = phi[mt8 & 1], alo = plo[mt8 & 1];
        if (mt8 < 14) {
            const size_t arow = ((size_t)(b0 + mt8 + 2) * 16 + m) * 64;
            phi[mt8 & 1] = *reinterpret_cast<const bf16x8*>(&At[arow + g * 8]);
            plo[mt8 & 1] = *reinterpret_cast<const bf16x8*>(&At[arow + 32 + g * 8]);
        }
        const int b = b0 + mt8;
#pragma unroll
        for (int nt = 0; nt < 2; ++nt) {
            f32x4 t = (f32x4){0.f, 0.f, 0.f, 0.f};
            t = __builtin_amdgcn_mfma_f32_16x16x32_bf16(ahi, wf[nt], t, 0, 0, 0);
            t = __builtin_amdgcn_mfma_f32_16x16x32_bf16(alo, wf[nt], t, 0, 0, 0);
            const float vpx = vp[mt8 * VP_STRIDE + nt * 48 + 3 * m + 0];
            const float vpy = vp[mt8 * VP_STRIDE + nt * 48 + 3 * m + 1];
            const float vpz = vp[mt8 * VP_STRIDE + nt * 48 + 3 * m + 2];
            const float o = fmaf(t[0], vpx, fmaf(t[1], vpy, fmaf(t[2], vpz, t[3])));
            const int vv = vbase + nt * 16 + m;
            if (g < 3 && vv < V_)
                out[((size_t)b * V_ + vv) * 3 + g] = o;
        }
    }
}

// ---------------------------------------------------------------------------
extern "C" void kernel_launch(void* const* d_in, const int* in_sizes, int n_in,
                              void* d_out, int out_size, void* d_ws, size_t ws_size,
                              hipStream_t stream)
{
    const float* betas         = (const float*)d_in[0];
    const float* body_pose     = (const float*)d_in[1];
    const float* global_orient = (const float*)d_in[2];
    const float* transl        = (const float*)d_in[3];
    const float* v_template    = (const float*)d_in[4];
    const float* shapedirs     = (const float*)d_in[5];
    const float* posedirs      = (const float*)d_in[6];
    const float* J_regressor   = (const float*)d_in[7];
    const float* lbs_weights   = (const float*)d_in[8];

    float* out = (float*)d_out;
    float* ws  = (float*)d_ws;

    // ws layout: JS[720] JT[72] f32 | pf bf16 [512*224] | At bf16 [8192*64]
    //            | pdT bf16 [CPAD*224] | vp f32 [512*CPAD]
    float* JS = ws;
    float* JT = ws + 720;
    unsigned short* pfw = (unsigned short*)(ws + 792);
    unsigned short* Atw = pfw + (size_t)B_ * KPAD;
    unsigned short* pdT = Atw + (size_t)B_ * 16 * 64;
    float* vpw = (float*)(pdT + (size_t)CPAD * KPAD);

    const size_t needed = 792u * 4 + (size_t)B_ * KPAD * 2
                        + (size_t)B_ * 16 * 64 * 2
                        + (size_t)CPAD * KPAD * 2
                        + (size_t)B_ * CPAD * 4;         // ~53.0 MB
    const bool pre = (ws_size >= needed);

    float* joints = out + (size_t)B_ * V_ * 3;

    k_pre <<<NCVT + 72, 256, 0, stream>>>(posedirs, shapedirs, J_regressor,
                                          v_template, pdT, JS, JT, pre ? 1 : 0);
    k_pose<<<B_ / 4, 256, 0, stream>>>(betas, body_pose, global_orient, transl,
                                       JS, JT, Atw, pfw, joints);
    if (pre) {
        k_g1 <<<1728, 256, 0, stream>>>(v_template, pdT, pfw, vpw);
        k_lbs<<<1728, 256, 0, stream>>>(lbs_weights, Atw, vpw, out);
    } else {
        k_fused_fb<<<1728, 256, 0, stream>>>(v_template, posedirs, shapedirs,
                                             lbs_weights, pfw, Atw, out);
    }
}

// Round 12
// 69.965 us; speedup vs baseline: 1.3335x; 1.0484x over previous
//
#include <hip/hip_runtime.h>
#include <math.h>

#define B_    512
#define V_    6890
#define J_    24
#define NB_   10
#define K_    207     // 9*(J-1)
#define KPAD  224     // slots 207..216 = betas x shapedirs, 217..223 zero
#define NCOL  20670   // V*3
#define TV    32      // verts per g1 block tile
#define TC    96      // cols per g1 block tile (TV*3)
#define CPAD  20736   // 216*96 = 108*192
#define NCVT  2268    // 324 * 7 cvt blocks
#define SPD_STRIDE 232   // s_pd k-stride in halves (224 + 8 pad)
#define VPL_STRIDE 200   // k_lbs LDS vp col stride in SHORTS (192 + 8 pad)
#define VP_STRIDE  104   // g1/fallback LDS vp stride in floats (96 + 8)

typedef __attribute__((ext_vector_type(8))) __bf16 bf16x8;
typedef __attribute__((ext_vector_type(4))) float  f32x4;

__constant__ int c_par[24] = {-1,0,0,0,1,2,3,4,5,6,7,8,9,9,9,12,13,14,16,17,18,19,20,21};
__constant__ int c_lev[24] = { 0,1,1,1,2,2,2,3,3,3,4,4,4,4,4, 5, 5, 5, 6, 6, 7, 7, 8, 8};

__device__ __forceinline__ unsigned short f2bf(float x) {
    union { float f; unsigned u; } v; v.f = x;
    unsigned r = (v.u + 0x7FFFu + ((v.u >> 16) & 1u)) >> 16;
    return (unsigned short)r;
}
__device__ __forceinline__ float bf2f(unsigned short h) {
    union { unsigned u; float f; } v; v.u = (unsigned)h << 16;
    return v.f;
}
__device__ __forceinline__ void wsync() {
    asm volatile("s_waitcnt lgkmcnt(0)" ::: "memory");
}

// ---------------------------------------------------------------------------
// K_PRE (fused): blocks [0, NCVT):      posedirs/shapedirs -> pdT bf16
//                blocks [NCVT,NCVT+72): JT/JS reduction
// ---------------------------------------------------------------------------
__global__ __launch_bounds__(256) void k_pre(const float* __restrict__ pd,
                                             const float* __restrict__ sd,
                                             const float* __restrict__ Jreg,
                                             const float* __restrict__ vt,
                                             unsigned short* __restrict__ pdT,
                                             float* __restrict__ JS,
                                             float* __restrict__ JT,
                                             int do_cvt)
{
    const int tid = threadIdx.x;
    const int bx  = blockIdx.x;

    if (bx < NCVT) {
        if (!do_cvt) return;
        const int c  = (bx % 324) * 64 + (tid & 63);
        const int kq = (bx / 324) * 4 + (tid >> 6);   // 0..27
        unsigned short u[8];
#pragma unroll
        for (int e = 0; e < 8; ++e) {
            const int k = kq * 8 + e;
            float x = 0.f;
            if (c < NCOL) {
                if (k < K_)            x = pd[(size_t)k * NCOL + c];
                else if (k < K_ + NB_) x = sd[(size_t)c * NB_ + (k - K_)];
            }
            u[e] = f2bf(x);
        }
        *reinterpret_cast<uint4*>(&pdT[(size_t)c * KPAD + kq * 8]) =
            *reinterpret_cast<const uint4*>(u);
        return;
    }

    // ---- jreg part ----
    const int jk = bx - NCVT;           // 0..71
    const int j = jk / 3, k = jk % 3;
    float acc[11];
#pragma unroll
    for (int i = 0; i < 11; ++i) acc[i] = 0.f;

#pragma unroll 4
    for (int v = tid; v < V_; v += 256) {
        const float r = Jreg[j * V_ + v];
        acc[0] = fmaf(r, vt[v * 3 + k], acc[0]);
        const float* s = &sd[(v * 3 + k) * NB_];
#pragma unroll
        for (int l = 0; l < NB_; ++l) acc[1 + l] = fmaf(r, s[l], acc[1 + l]);
    }

    __shared__ float red[4][11];
    const int lane = tid & 63, w = tid >> 6;
#pragma unroll
    for (int i = 0; i < 11; ++i) {
        float a = acc[i];
        for (int off = 32; off; off >>= 1) a += __shfl_xor(a, off, 64);
        acc[i] = a;
    }
    if (lane == 0) {
#pragma unroll
        for (int i = 0; i < 11; ++i) red[w][i] = acc[i];
    }
    __syncthreads();
    if (tid == 0) {
        for (int i = 0; i < 11; ++i) {
            const float s = red[0][i] + red[1][i] + red[2][i] + red[3][i];
            if (i == 0) JT[j * 3 + k] = s;
            else        JS[(j * 3 + k) * NB_ + (i - 1)] = s;
        }
    }
}

// ---------------------------------------------------------------------------
// K_POSE: joint pipeline, one wave per batch. grid = 128 x 256.
// ---------------------------------------------------------------------------
__global__ __launch_bounds__(256) void k_pose(const float* __restrict__ betas,
                                              const float* __restrict__ body_pose,
                                              const float* __restrict__ global_orient,
                                              const float* __restrict__ transl,
                                              const float* __restrict__ JS,
                                              const float* __restrict__ JT,
                                              unsigned short* __restrict__ Atout,
                                              unsigned short* __restrict__ pfout,
                                              float* __restrict__ joints_out)
{
    const int wv   = threadIdx.x >> 6;
    const int j    = threadIdx.x & 63;
    const int b    = blockIdx.x * 4 + wv;

    __shared__ float sR[4][24][9];
    __shared__ float sJ[4][24][3];
    __shared__ float sTl[4][24][12];
    __shared__ float sTg[4][24][12];

    if (j < 24) {
        float rx, ry, rz;
        if (j == 0) {
            rx = global_orient[b * 3 + 0];
            ry = global_orient[b * 3 + 1];
            rz = global_orient[b * 3 + 2];
        } else {
            const float* p = &body_pose[b * 69 + (j - 1) * 3];
            rx = p[0]; ry = p[1]; rz = p[2];
        }
        const float ax = rx + 1e-8f, ay = ry + 1e-8f, az = rz + 1e-8f;
        const float angle = sqrtf(ax * ax + ay * ay + az * az);
        const float inv = 1.f / angle;
        const float x = rx * inv, y = ry * inv, z = rz * inv;
        const float s = sinf(angle), c = cosf(angle), t = 1.f - c;

        float R[9];
        R[0] = 1.f - t * (y * y + z * z);
        R[1] = -s * z + t * x * y;
        R[2] =  s * y + t * x * z;
        R[3] =  s * z + t * x * y;
        R[4] = 1.f - t * (x * x + z * z);
        R[5] = -s * x + t * y * z;
        R[6] = -s * y + t * x * z;
        R[7] =  s * x + t * y * z;
        R[8] = 1.f - t * (x * x + y * y);

#pragma unroll
        for (int e = 0; e < 9; ++e) sR[wv][j][e] = R[e];

        if (j >= 1) {
#pragma unroll
            for (int e = 0; e < 9; ++e) {
                const float id = (e == 0 || e == 4 || e == 8) ? 1.f : 0.f;
                pfout[b * KPAD + (j - 1) * 9 + e] = f2bf(R[e] - id);
            }
        }
#pragma unroll
        for (int k = 0; k < 3; ++k) {
            float jr = JT[j * 3 + k];
#pragma unroll
            for (int l = 0; l < NB_; ++l)
                jr = fmaf(betas[b * NB_ + l], JS[(j * 3 + k) * NB_ + l], jr);
            sJ[wv][j][k] = jr;
        }
    }
    if (j < KPAD - K_) {
        const float val = (j < NB_) ? betas[b * NB_ + j] : 0.f;
        pfout[b * KPAD + K_ + j] = f2bf(val);
    }
    wsync();

    if (j < 24) {
        const int p = c_par[j];
        float t0 = sJ[wv][j][0], t1 = sJ[wv][j][1], t2 = sJ[wv][j][2];
        if (j > 0) { t0 -= sJ[wv][p][0]; t1 -= sJ[wv][p][1]; t2 -= sJ[wv][p][2]; }
        sTl[wv][j][0] = sR[wv][j][0]; sTl[wv][j][1] = sR[wv][j][1];
        sTl[wv][j][2] = sR[wv][j][2]; sTl[wv][j][3] = t0;
        sTl[wv][j][4] = sR[wv][j][3]; sTl[wv][j][5] = sR[wv][j][4];
        sTl[wv][j][6] = sR[wv][j][5]; sTl[wv][j][7] = t1;
        sTl[wv][j][8] = sR[wv][j][6]; sTl[wv][j][9] = sR[wv][j][7];
        sTl[wv][j][10] = sR[wv][j][8]; sTl[wv][j][11] = t2;
    }
    wsync();

    if (j == 0) {
#pragma unroll
        for (int e = 0; e < 12; ++e) sTg[wv][0][e] = sTl[wv][0][e];
    }
    wsync();

    for (int lev = 1; lev <= 8; ++lev) {
        if (j < 24 && c_lev[j] == lev) {
            const int p = c_par[j];
            float o[12];
#pragma unroll
            for (int r = 0; r < 3; ++r) {
#pragma unroll
                for (int c = 0; c < 4; ++c) {
                    float v = (c == 3) ? sTg[wv][p][r * 4 + 3] : 0.f;
#pragma unroll
                    for (int m = 0; m < 3; ++m)
                        v = fmaf(sTg[wv][p][r * 4 + m], sTl[wv][j][m * 4 + c], v);
                    o[r * 4 + c] = v;
                }
            }
#pragma unroll
            for (int e = 0; e < 12; ++e) sTg[wv][j][e] = o[e];
        }
        wsync();
    }

    if (j < 24) {
        float corr[3];
#pragma unroll
        for (int r = 0; r < 3; ++r)
            corr[r] = sTg[wv][j][r * 4 + 0] * sJ[wv][j][0]
                    + sTg[wv][j][r * 4 + 1] * sJ[wv][j][1]
                    + sTg[wv][j][r * 4 + 2] * sJ[wv][j][2];

#pragma unroll
        for (int r = 0; r < 3; ++r) {
            float row[4];
            row[0] = sTg[wv][j][r * 4 + 0];
            row[1] = sTg[wv][j][r * 4 + 1];
            row[2] = sTg[wv][j][r * 4 + 2];
            row[3] = sTg[wv][j][r * 4 + 3] - corr[r] + transl[b * 3 + r];
#pragma unroll
            for (int cc = 0; cc < 4; ++cc) {
                const float val = row[cc];
                const unsigned short hi = f2bf(val);
                const unsigned short lo = f2bf(val - bf2f(hi));
                const size_t base = ((size_t)b * 16 + r * 4 + cc) * 64;
                Atout[base + j]      = hi;
                Atout[base + 32 + j] = lo;
            }
        }
#pragma unroll
        for (int k = 0; k < 3; ++k)
            joints_out[(b * 24 + j) * 3 + k] = sTg[wv][j][k * 4 + 3] + transl[b * 3 + k];
    }
    for (int idx = j; idx < 1024; idx += 64) {
        const int e = idx >> 6, jj = idx & 63;
        if (e >= 12 || (jj & 31) >= 24)
            Atout[((size_t)b * 16 + e) * 64 + jj] = 0;
    }
}

// ---------------------------------------------------------------------------
// K_G1: pure GEMM1 (round-8 structure), vp written as BF16 (halved traffic).
// grid = 1728 (216 vtiles x 8 btiles, XCD-chunked), block 256 (4 waves).
// LDS: s_pd [96][232] bf16 = 44544 B (vp alias [4][16][104] f32 = 26.6 KB).
// Store: full-row 192B segments of bf16, uint4 per lane (no partial-line RFO;
// the shared boundary line of adjacent vtiles merges in same-XCD L2).
// ---------------------------------------------------------------------------
__global__ __launch_bounds__(256, 3) void k_g1(
    const float* __restrict__ v_template,        // flat [NCOL]
    const unsigned short* __restrict__ pdT,      // bf16 [CPAD][KPAD]
    const unsigned short* __restrict__ pf,       // bf16 [B][KPAD]
    unsigned short* __restrict__ vp_ws)          // bf16 [B][CPAD]
{
    __shared__ __align__(16) char smem[44544];
    unsigned short* s_pd = (unsigned short*)smem;
    float*          s_vp = (float*)smem;         // alias after barrier

    const int tid = threadIdx.x;
    const int l   = tid & 63;
    const int wv  = tid >> 6;
    const int m   = l & 15;
    const int g   = l >> 4;

    const int lraw  = blockIdx.x;                 // 1728 % 8 == 0 -> bijective
    const int gl    = (lraw & 7) * 216 + (lraw >> 3);
    const int vtile = gl >> 3;                    // 0..215
    const int btile = gl & 7;                     // 0..7
    const int bbase = btile * 64;
    const int vb3   = vtile * TC;

    // ---- stage full pdT tile: 96 cols x 224 k = 2688 uint4, all in flight ----
#pragma unroll
    for (int i = 0; i < 11; ++i) {
        const int idx = i * 256 + tid;
        if (i == 10 && tid >= 128) break;         // 2688 = 10*256 + 128
        const int col = idx / 28, kq = idx % 28;
        const uint4 val = *reinterpret_cast<const uint4*>(
            &pdT[(size_t)(vb3 + col) * KPAD + kq * 8]);
        *reinterpret_cast<uint4*>(&s_pd[col * SPD_STRIDE + kq * 8]) = val;
    }

    // ---- prefetch all 7 A-frags while staging drains ----
    bf16x8 af[7];
#pragma unroll
    for (int ck = 0; ck < 7; ++ck)
        af[ck] = *reinterpret_cast<const bf16x8*>(
            &pf[(size_t)(bbase + wv * 16 + m) * KPAD + ck * 32 + g * 8]);

    __syncthreads();

    // ---- GEMM1: 42 ds_read + 42 MFMA ----
    f32x4 acc1[6];
#pragma unroll
    for (int i = 0; i < 6; ++i) acc1[i] = (f32x4){0.f, 0.f, 0.f, 0.f};

#pragma unroll
    for (int ck = 0; ck < 7; ++ck) {
        const unsigned short* pb = &s_pd[m * SPD_STRIDE + ck * 32 + g * 8];
#pragma unroll
        for (int nt = 0; nt < 6; ++nt) {
            const bf16x8 bfr = *reinterpret_cast<const bf16x8*>(
                &pb[nt * 16 * SPD_STRIDE]);
            acc1[nt] = __builtin_amdgcn_mfma_f32_16x16x32_bf16(af[ck], bfr, acc1[nt], 0, 0, 0);
        }
    }

    __syncthreads();   // all waves done reading s_pd before alias overwrite

    // ---- dump to per-wave LDS [16][104] f32 (+v_template) ----
    float* vp = &s_vp[wv * 16 * VP_STRIDE];
#pragma unroll
    for (int nt = 0; nt < 6; ++nt) {
        const int c = vb3 + nt * 16 + m;
        const float vtf = (c < NCOL) ? v_template[c] : 0.f;
#pragma unroll
        for (int r = 0; r < 4; ++r)
            vp[(g * 4 + r) * VP_STRIDE + nt * 16 + m] = acc1[nt][r] + vtf;
    }
    wsync();           // wave-private region

    // ---- coalesced bf16 store: 16 rows x 12 uint4 per wave, 3 per lane ----
    const int b0 = bbase + wv * 16;
#pragma unroll
    for (int i = 0; i < 3; ++i) {
        const int idx = i * 64 + l;               // 0..191
        const int rb = idx / 12, q = idx % 12;    // row, 8-col group
        const float* src = &vp[rb * VP_STRIDE + q * 8];
        unsigned short u[8];
#pragma unroll
        for (int e = 0; e < 8; ++e) u[e] = f2bf(src[e]);
        *reinterpret_cast<uint4*>(&vp_ws[(size_t)(b0 + rb) * CPAD + vb3 + q * 8]) =
            *reinterpret_cast<const uint4*>(u);
    }
}

// ---------------------------------------------------------------------------
// K_LBS: GEMM2 + combine, bf16 vp staged to LDS in ONE coalesced round trip.
// grid = 1728 (108 vtiles64 x 16 btiles32, XCD-chunked), block 256 (4 waves).
// LDS: s_vp [32][200] bf16 = 12.8 KB + s_w [64][32] bf16 = 4 KB.
// ---------------------------------------------------------------------------
__global__ __launch_bounds__(256, 5) void k_lbs(
    const float* __restrict__ lbs_weights,       // [V][24]
    const unsigned short* __restrict__ At,       // bf16 [B*16][64] hi|lo
    const unsigned short* __restrict__ vp_ws,    // bf16 [B][CPAD]
    float* __restrict__ out)                     // [B][V][3]
{
    __shared__ __align__(16) unsigned short s_vph[32 * VPL_STRIDE];  // 12.8 KB
    __shared__ unsigned short s_w[64 * 32];                          // 4 KB

    const int tid = threadIdx.x;
    const int wv  = tid >> 6;
    const int m   = tid & 15;
    const int g   = (tid & 63) >> 4;

    const int lraw  = blockIdx.x;                 // 1728 % 8 == 0 -> bijective
    const int gl    = (lraw & 7) * 216 + (lraw >> 3);
    const int vtile = gl >> 4;                    // 0..107 (64 verts)
    const int btile = gl & 15;                    // 0..15  (32 batches)
    const int vbase = vtile * 64;
    const int bbase = btile * 32;
    const int vb3   = vtile * 192;

    // ---- stage vp tile [32 b][192 cols] bf16 = 768 uint4 (32 x 24/row),
    //      3 x 256 threads, all loads in flight, one drain ----
#pragma unroll
    for (int it = 0; it < 3; ++it) {
        const int idx = it * 256 + tid;
        const int row = idx / 24, q = idx % 24;
        const uint4 val = *reinterpret_cast<const uint4*>(
            &vp_ws[(size_t)(bbase + row) * CPAD + vb3 + q * 8]);
        *reinterpret_cast<uint4*>(&s_vph[row * VPL_STRIDE + q * 8]) = val;
    }

    // ---- stage W: lbs_weights -> bf16 [64][32] ----
    {
        const int v  = tid >> 2, jq = tid & 3;
        const int vv = vbase + v;
        const int vc = vv < V_ ? vv : V_ - 1;
        unsigned short u[8];
        if (jq < 3) {
            const float* src = &lbs_weights[vc * 24 + jq * 8];
#pragma unroll
            for (int e = 0; e < 8; ++e) u[e] = f2bf(src[e]);
        } else {
#pragma unroll
            for (int e = 0; e < 8; ++e) u[e] = 0;
        }
        *reinterpret_cast<uint4*>(&s_w[v * 32 + jq * 8]) =
            *reinterpret_cast<const uint4*>(u);
    }
    __syncthreads();

    bf16x8 wf[4];
#pragma unroll
    for (int nt = 0; nt < 4; ++nt)
        wf[nt] = *reinterpret_cast<const bf16x8*>(&s_w[(nt * 16 + m) * 32 + g * 8]);

    // ---- 8 batches per wave, At prefetch depth-2 (static ring) ----
    const int b0 = bbase + wv * 8;
    bf16x8 phi[2], plo[2];
#pragma unroll
    for (int p = 0; p < 2; ++p) {
        const size_t arow = ((size_t)(b0 + p) * 16 + m) * 64;
        phi[p] = *reinterpret_cast<const bf16x8*>(&At[arow + g * 8]);
        plo[p] = *reinterpret_cast<const bf16x8*>(&At[arow + 32 + g * 8]);
    }

#pragma unroll
    for (int mt = 0; mt < 8; ++mt) {
        const bf16x8 ahi = phi[mt & 1], alo = plo[mt & 1];
        if (mt < 6) {
            const size_t arow = ((size_t)(b0 + mt + 2) * 16 + m) * 64;
            phi[mt & 1] = *reinterpret_cast<const bf16x8*>(&At[arow + g * 8]);
            plo[mt & 1] = *reinterpret_cast<const bf16x8*>(&At[arow + 32 + g * 8]);
        }
        const int b = b0 + mt;
        const unsigned short* vpb = &s_vph[(wv * 8 + mt) * VPL_STRIDE];
#pragma unroll
        for (int nt = 0; nt < 4; ++nt) {
            f32x4 t = (f32x4){0.f, 0.f, 0.f, 0.f};
            t = __builtin_amdgcn_mfma_f32_16x16x32_bf16(ahi, wf[nt], t, 0, 0, 0);
            t = __builtin_amdgcn_mfma_f32_16x16x32_bf16(alo, wf[nt], t, 0, 0, 0);
            const float vpx = bf2f(vpb[nt * 48 + 3 * m + 0]);  // stride-3 shorts,
            const float vpy = bf2f(vpb[nt * 48 + 3 * m + 1]);  // g-broadcast:
            const float vpz = bf2f(vpb[nt * 48 + 3 * m + 2]);  // conflict-free
            const float o = fmaf(t[0], vpx, fmaf(t[1], vpy, fmaf(t[2], vpz, t[3])));
            const int vv = vbase + nt * 16 + m;
            if (g < 3 && vv < V_)
                out[((size_t)b * V_ + vv) * 3 + g] = o;
        }
    }
}

// ---------------------------------------------------------------------------
// Fallback fused kernel (round-7 structure, f32-source staging) for small ws.
// ---------------------------------------------------------------------------
__global__ __launch_bounds__(256, 3) void k_fused_fb(
    const float* __restrict__ v_template,
    const float* __restrict__ posedirs,
    const float* __restrict__ shapedirs,
    const float* __restrict__ lbs_weights,
    const unsigned short* __restrict__ pf,
    const unsigned short* __restrict__ At,
    float* __restrict__ out)
{
    __shared__ __align__(16) char smem[44544 + 2048];
    unsigned short* s_pd = (unsigned short*)smem;
    unsigned short* s_w  = (unsigned short*)(smem + 44544);
    float*          s_vp = (float*)smem;

    const int tid = threadIdx.x;
    const int l   = tid & 63;
    const int wv  = tid >> 6;
    const int m   = l & 15;
    const int g   = l >> 4;

    const int lraw  = blockIdx.x;
    const int gl    = (lraw & 7) * 216 + (lraw >> 3);
    const int vtile = gl >> 3;
    const int btile = gl & 7;
    const int vbase = vtile * TV;
    const int bbase = btile * 64;
    const int vb3   = vtile * TC;

    if (tid < 128) {
        const int v  = tid >> 2, jq = tid & 3;
        const int vv = vbase + v;
        const int vc = vv < V_ ? vv : V_ - 1;
        unsigned short u[8];
        if (jq < 3) {
            const float* src = &lbs_weights[vc * 24 + jq * 8];
#pragma unroll
            for (int e = 0; e < 8; ++e) u[e] = f2bf(src[e]);
        } else {
#pragma unroll
            for (int e = 0; e < 8; ++e) u[e] = 0;
        }
        *reinterpret_cast<uint4*>(&s_w[v * 32 + jq * 8]) =
            *reinterpret_cast<const uint4*>(u);
    }

#pragma unroll
    for (int i = 0; i < 11; ++i) {
        const int idx = i * 256 + tid;
        if (i == 10 && tid >= 128) break;
        const int col = idx / 28, kq = idx % 28;
        unsigned short u[8];
        const int c = vb3 + col;
#pragma unroll
        for (int e = 0; e < 8; ++e) {
            const int k = kq * 8 + e;
            float x = 0.f;
            if (c < NCOL) {
                if (k < K_)            x = posedirs[(size_t)k * NCOL + c];
                else if (k < K_ + NB_) x = shapedirs[(size_t)c * NB_ + (k - K_)];
            }
            u[e] = f2bf(x);
        }
        *reinterpret_cast<uint4*>(&s_pd[col * SPD_STRIDE + kq * 8]) =
            *reinterpret_cast<const uint4*>(u);
    }

    bf16x8 af[7];
#pragma unroll
    for (int ck = 0; ck < 7; ++ck)
        af[ck] = *reinterpret_cast<const bf16x8*>(
            &pf[(size_t)(bbase + wv * 16 + m) * KPAD + ck * 32 + g * 8]);

    __syncthreads();

    f32x4 acc1[6];
#pragma unroll
    for (int i = 0; i < 6; ++i) acc1[i] = (f32x4){0.f, 0.f, 0.f, 0.f};
#pragma unroll
    for (int ck = 0; ck < 7; ++ck) {
        const unsigned short* pb = &s_pd[m * SPD_STRIDE + ck * 32 + g * 8];
#pragma unroll
        for (int nt = 0; nt < 6; ++nt) {
            const bf16x8 bfr = *reinterpret_cast<const bf16x8*>(&pb[nt * 16 * SPD_STRIDE]);
            acc1[nt] = __builtin_amdgcn_mfma_f32_16x16x32_bf16(af[ck], bfr, acc1[nt], 0, 0, 0);
        }
    }
    __syncthreads();

    float* vp = &s_vp[wv * 16 * VP_STRIDE];
#pragma unroll
    for (int nt = 0; nt < 6; ++nt) {
        const int c = vb3 + nt * 16 + m;
        const float vtf = (c < NCOL) ? v_template[c] : 0.f;
#pragma unroll
        for (int r = 0; r < 4; ++r)
            vp[(g * 4 + r) * VP_STRIDE + nt * 16 + m] = acc1[nt][r] + vtf;
    }
    wsync();

    bf16x8 wf[2];
#pragma unroll
    for (int nt = 0; nt < 2; ++nt)
        wf[nt] = *reinterpret_cast<const bf16x8*>(&s_w[(nt * 16 + m) * 32 + g * 8]);

    const int b0 = bbase + wv * 16;
    bf16x8 phi[2], plo[2];
#pragma unroll
    for (int p = 0; p < 2; ++p) {
        const size_t arow = ((size_t)(b0 + p) * 16 + m) * 64;
        phi[p] = *reinterpret_cast<const bf16x8*>(&At[arow + g * 8]);
        plo[p] = *reinterpret_cast<const bf16x8*>(&At[arow + 32 + g * 8]);
    }
#pragma unroll
    for (int mt8 = 0; mt8 < 16; ++mt8) {
        const bf16x8 ahi = phi[mt8 & 1], alo = plo[mt8 & 1];
        if (mt8 < 14) {
            const size_t arow = ((size_t)(b0 + mt8 + 2) * 16 + m) * 64;
            phi[mt8 & 1] = *reinterpret_cast<const bf16x8*>(&At[arow + g * 8]);
            plo[mt8 & 1] = *reinterpret_cast<const bf16x8*>(&At[arow + 32 + g * 8]);
        }
        const int b = b0 + mt8;
#pragma unroll
        for (int nt = 0; nt < 2; ++nt) {
            f32x4 t = (f32x4){0.f, 0.f, 0.f, 0.f};
            t = __builtin_amdgcn_mfma_f32_16x16x32_bf16(ahi, wf[nt], t, 0, 0, 0);
            t = __builtin_amdgcn_mfma_f32_16x16x32_bf16(alo, wf[nt], t, 0, 0, 0);
            const float vpx = vp[mt8 * VP_STRIDE + nt * 48 + 3 * m + 0];
            const float vpy = vp[mt8 * VP_STRIDE + nt * 48 + 3 * m + 1];
            const float vpz = vp[mt8 * VP_STRIDE + nt * 48 + 3 * m + 2];
            const float o = fmaf(t[0], vpx, fmaf(t[1], vpy, fmaf(t[2], vpz, t[3])));
            const int vv = vbase + nt * 16 + m;
            if (g < 3 && vv < V_)
                out[((size_t)b * V_ + vv) * 3 + g] = o;
        }
    }
}

// ---------------------------------------------------------------------------
extern "C" void kernel_launch(void* const* d_in, const int* in_sizes, int n_in,
                              void* d_out, int out_size, void* d_ws, size_t ws_size,
                              hipStream_t stream)
{
    const float* betas         = (const float*)d_in[0];
    const float* body_pose     = (const float*)d_in[1];
    const float* global_orient = (const float*)d_in[2];
    const float* transl        = (const float*)d_in[3];
    const float* v_template    = (const float*)d_in[4];
    const float* shapedirs     = (const float*)d_in[5];
    const float* posedirs      = (const float*)d_in[6];
    const float* J_regressor   = (const float*)d_in[7];
    const float* lbs_weights   = (const float*)d_in[8];

    float* out = (float*)d_out;
    float* ws  = (float*)d_ws;

    // ws layout: JS[720] JT[72] f32 | pf bf16 [512*224] | At bf16 [8192*64]
    //            | pdT bf16 [CPAD*224] | vp bf16 [512*CPAD]
    float* JS = ws;
    float* JT = ws + 720;
    unsigned short* pfw = (unsigned short*)(ws + 792);
    unsigned short* Atw = pfw + (size_t)B_ * KPAD;
    unsigned short* pdT = Atw + (size_t)B_ * 16 * 64;
    unsigned short* vpw = pdT + (size_t)CPAD * KPAD;

    const size_t needed = 792u * 4 + (size_t)B_ * KPAD * 2
                        + (size_t)B_ * 16 * 64 * 2
                        + (size_t)CPAD * KPAD * 2
                        + (size_t)B_ * CPAD * 2;         // ~31.8 MB
    const bool pre = (ws_size >= needed);

    float* joints = out + (size_t)B_ * V_ * 3;

    k_pre <<<NCVT + 72, 256, 0, stream>>>(posedirs, shapedirs, J_regressor,
                                          v_template, pdT, JS, JT, pre ? 1 : 0);
    k_pose<<<B_ / 4, 256, 0, stream>>>(betas, body_pose, global_orient, transl,
                                       JS, JT, Atw, pfw, joints);
    if (pre) {
        k_g1 <<<1728, 256, 0, stream>>>(v_template, pdT, pfw, vpw);
        k_lbs<<<1728, 256, 0, stream>>>(lbs_weights, Atw, vpw, out);
    } else {
        k_fused_fb<<<1728, 256, 0, stream>>>(v_template, posedirs, shapedirs,
                                             lbs_weights, pfw, Atw, out);
    }
}